// Round 1
// baseline (2841.338 us; speedup 1.0000x reference)
//
#include <hip/hip_runtime.h>

#define NF 768
#define D1 10
#define D2 128
#define GD 384

static __device__ __forceinline__ float sigf(float v){ return 1.0f/(1.0f+__expf(-v)); }

// ---- degree via atomics (deg buffer pre-zeroed; self-loop added in k_dinv) ----
__global__ void k_deg(const int* __restrict__ dst, float* __restrict__ deg, int E){
    int e = blockIdx.x*256 + threadIdx.x;
    if(e<E) atomicAdd(&deg[dst[e]], 1.0f);
}

__global__ void k_dinv(float* deg, int N){
    int n = blockIdx.x*256 + threadIdx.x;
    if(n<N) deg[n] = rsqrtf(deg[n]+1.0f);   // +1 = self loop; always >0
}

// ---- h1 = x @ W1  (15000x768 @ 768x10), one wave per row ----
__global__ __launch_bounds__(256) void k_h1(const float* __restrict__ x,
                                            const float* __restrict__ W1,
                                            float* __restrict__ h1, int N){
    __shared__ float w1s[NF*D1];
    for(int i=threadIdx.x;i<NF*D1;i+=256) w1s[i]=W1[i];
    __syncthreads();
    int row = blockIdx.x*4 + (threadIdx.x>>6);
    int lane = threadIdx.x&63;
    if(row>=N) return;
    const float* xr = x + (size_t)row*NF;
    float acc[D1];
#pragma unroll
    for(int c=0;c<D1;c++) acc[c]=0.f;
#pragma unroll
    for(int i=0;i<NF/64;i++){
        float xa = xr[lane+64*i];
        const float* w = &w1s[(lane+64*i)*D1];
#pragma unroll
        for(int c=0;c<D1;c++) acc[c] += xa*w[c];
    }
#pragma unroll
    for(int c=0;c<D1;c++){
        float v=acc[c];
#pragma unroll
        for(int off=32;off;off>>=1) v += __shfl_down(v,off,64);
        if(lane==0) h1[(size_t)row*D1+c]=v;
    }
}

// ---- scatter layer 1: agg1[dst] += h1[src]*norm ----
__global__ void k_scat1(const int* __restrict__ src, const int* __restrict__ dst,
                        const float* __restrict__ dinv, const float* __restrict__ h1,
                        float* __restrict__ agg1, int E){
    int gid = blockIdx.x*256 + threadIdx.x;
    if(gid >= E*D1) return;
    int e = gid/D1, c = gid - e*D1;
    int s = src[e], d = dst[e];
    float norm = dinv[s]*dinv[d];
    atomicAdd(&agg1[(size_t)d*D1+c], h1[(size_t)s*D1+c]*norm);
}

// ---- h = relu(agg1 + selfloop + b1), in place into agg1 ----
__global__ void k_relu(float* __restrict__ agg1, const float* __restrict__ h1,
                       const float* __restrict__ dinv, const float* __restrict__ b1, int N){
    int gid = blockIdx.x*256 + threadIdx.x;
    if(gid >= N*D1) return;
    int n = gid/D1, c = gid - n*D1;
    float di = dinv[n];
    float v = agg1[gid] + h1[gid]*di*di + b1[c];
    agg1[gid] = v>0.f ? v : 0.f;
}

// ---- hz = h @ W2  (15000x10 @ 10x128), block per node ----
__global__ __launch_bounds__(128) void k_hz(const float* __restrict__ h,
                                            const float* __restrict__ W2,
                                            float* __restrict__ hz, int N){
    __shared__ float w2s[D1*D2];
    int j = threadIdx.x;
    for(int i=j;i<D1*D2;i+=128) w2s[i]=W2[i];
    __syncthreads();
    int n = blockIdx.x;
    if(n>=N) return;
    const float* hr = h + (size_t)n*D1;
    float acc=0.f;
#pragma unroll
    for(int k=0;k<D1;k++) acc += hr[k]*w2s[k*D2+j];
    hz[(size_t)n*D2+j]=acc;
}

// ---- scatter layer 2: zagg[dst] += hz[src]*norm, 128 threads per edge ----
__global__ void k_scat2(const int* __restrict__ src, const int* __restrict__ dst,
                        const float* __restrict__ dinv, const float* __restrict__ hz,
                        float* __restrict__ zagg, int E){
    int gid = blockIdx.x*256 + threadIdx.x;
    int e = gid>>7, c = gid&127;
    if(e>=E) return;
    int s=src[e], d=dst[e];
    float norm = dinv[s]*dinv[d];
    atomicAdd(&zagg[(size_t)d*D2+c], hz[(size_t)s*D2+c]*norm);
}

// ---- z = zagg + selfloop + b2, in place into zagg ----
__global__ void k_zfin(float* __restrict__ zagg, const float* __restrict__ hz,
                       const float* __restrict__ dinv, const float* __restrict__ b2, int N){
    int gid = blockIdx.x*256 + threadIdx.x;
    if(gid >= N*D2) return;
    int n = gid>>7, c = gid&127;
    float di = dinv[n];
    zagg[gid] = zagg[gid] + hz[gid]*di*di + b2[c];
}

// ---- zwh[n][jj] = z[n] . W_ih[rw(jj)][0:128]; zwt: cols 896:1024.  16 nodes/block, 384 thr ----
__global__ __launch_bounds__(384) void k_zw(const float* __restrict__ z,
                                            const float* __restrict__ Wih,
                                            float* __restrict__ zwh, float* __restrict__ zwt, int N){
    __shared__ float As[16*D2];
    int n0 = blockIdx.x*16;
    int tid = threadIdx.x;
    for(int idx=tid; idx<16*D2; idx+=384){
        int m=idx>>7, k=idx&127;
        As[idx] = (n0+m<N) ? z[(size_t)(n0+m)*D2 + k] : 0.f;
    }
    __syncthreads();
    int row = tid<128 ? tid : tid+128;   // rows 0:128 (i), 256:384 (g), 384:512 (o)
    const float* wh = Wih + (size_t)row*1024;
    const float* wt = wh + 896;
    float ah[16], at[16];
#pragma unroll
    for(int m=0;m<16;m++){ ah[m]=0.f; at[m]=0.f; }
    for(int k=0;k<D2;k++){
        float bh=wh[k], bt=wt[k];
#pragma unroll
        for(int m=0;m<16;m++){ float a=As[m*D2+k]; ah[m]+=a*bh; at[m]+=a*bt; }
    }
    for(int m=0;m<16;m++){
        if(n0+m<N){
            zwh[(size_t)(n0+m)*GD + tid] = ah[m];
            zwt[(size_t)(n0+m)*GD + tid] = at[m];
        }
    }
}

// ---- fused big GEMM (r_emb x W_ih[:,128:896]^T over 384 needed rows) + LSTM epilogue ----
// BM=32 triples, BN=384 (all), BK=32. 256 threads: x=tid&63 (col), y=tid>>6 (row grp).
// acc[r][c] covers row y+4r, col jj=x+64c. Lane x holds i_d,g_d,o_d for d=x and d=64+x.
#define BM 32
#define BK 32
#define LST 33
__global__ __launch_bounds__(256) void k_big(
    const float* __restrict__ remb, const float* __restrict__ Wih,
    const float* __restrict__ zwh, const float* __restrict__ zwt,
    const float* __restrict__ b_ih, const float* __restrict__ b_hh,
    const int* __restrict__ trip, float* __restrict__ score, int T){
    __shared__ float smem[BM*LST + GD*LST];   // 1056 + 12672 floats = 54.9 KB
    float* As = smem;
    float* Bs = smem + BM*LST;
    int tid = threadIdx.x;
    int x = tid & 63, y = tid >> 6;
    int t0 = blockIdx.x * BM;
    float acc[8][6];
#pragma unroll
    for(int r=0;r<8;r++)
#pragma unroll
        for(int c=0;c<6;c++) acc[r][c]=0.f;

    for(int k0=0;k0<NF;k0+=BK){
        { // A tile 32x32: one float4 per thread
            int row = tid>>3, kk=(tid&7)*4;
            int trow = t0+row; if(trow>=T) trow=T-1;
            const float4 v = *reinterpret_cast<const float4*>(&remb[(size_t)trow*NF + k0 + kk]);
            float* a = &As[row*LST+kk];
            a[0]=v.x; a[1]=v.y; a[2]=v.z; a[3]=v.w;
        }
#pragma unroll
        for(int i=0;i<12;i++){ // B tile 384x32: 12 float4 per thread
            int f = tid + 256*i;
            int jj = f>>3, kk=(f&7)*4;
            int rw = jj<128 ? jj : jj+128;
            const float4 v = *reinterpret_cast<const float4*>(&Wih[(size_t)rw*1024 + 128 + k0 + kk]);
            float* b = &Bs[jj*LST+kk];
            b[0]=v.x; b[1]=v.y; b[2]=v.z; b[3]=v.w;
        }
        __syncthreads();
#pragma unroll
        for(int k=0;k<BK;k++){
            float a[8], b[6];
#pragma unroll
            for(int r=0;r<8;r++) a[r]=As[(y+4*r)*LST + k];
#pragma unroll
            for(int c=0;c<6;c++) b[c]=Bs[(x+64*c)*LST + k];
#pragma unroll
            for(int r=0;r<8;r++)
#pragma unroll
                for(int c=0;c<6;c++) acc[r][c] += a[r]*b[c];
        }
        __syncthreads();
    }
    // epilogue: add gathered z-tables + bias, LSTM nonlinearity, wave-reduce row sums
#pragma unroll
    for(int r=0;r<8;r++){
        int rowi = y+4*r;
        int t = t0+rowi; int tc = (t<T)? t : T-1;
        int th = trip[3*tc], tt = trip[3*tc+2];
        const float* zh = zwh + (size_t)th*GD;
        const float* zt = zwt + (size_t)tt*GD;
        float v = 0.f;
#pragma unroll
        for(int half=0; half<2; half++){
            int d = x + 64*half;
            float ig = acc[r][0+half] + zh[d]     + zt[d]     + b_ih[d]     + b_hh[d];
            float gg = acc[r][2+half] + zh[128+d] + zt[128+d] + b_ih[256+d] + b_hh[256+d];
            float og = acc[r][4+half] + zh[256+d] + zt[256+d] + b_ih[384+d] + b_hh[384+d];
            float cc = sigf(ig)*tanhf(gg);
            v += sigf(og)*tanhf(cc);
        }
#pragma unroll
        for(int off=32;off;off>>=1) v += __shfl_down(v,off,64);
        if(x==0 && t<T) score[t] = sigf(v);
    }
}

extern "C" void kernel_launch(void* const* d_in, const int* in_sizes, int n_in,
                              void* d_out, int out_size, void* d_ws, size_t ws_size,
                              hipStream_t stream){
    const float* x    = (const float*)d_in[0];
    const float* remb = (const float*)d_in[1];
    const float* W1   = (const float*)d_in[2];
    const float* b1   = (const float*)d_in[3];
    const float* W2   = (const float*)d_in[4];
    const float* b2   = (const float*)d_in[5];
    const float* Wih  = (const float*)d_in[6];
    const float* b_ih = (const float*)d_in[8];
    const float* b_hh = (const float*)d_in[9];
    const int*   ei   = (const int*)d_in[10];
    const int*   trip = (const int*)d_in[11];
    float* score = (float*)d_out;

    const int N = in_sizes[0]/NF;       // 15000
    const int E = in_sizes[10]/2;       // 200000
    const int T = in_sizes[11]/3;       // 100000
    const int* src = ei;
    const int* dst = ei + E;

    // workspace layout (floats)
    float* ws = (float*)d_ws;
    size_t o = 0;
    float* dinv = ws + o; o += (size_t)((N+7)&~7);
    float* h1   = ws + o; o += (size_t)N*D1;
    float* agg1 = ws + o; o += (size_t)N*D1;      // becomes h after relu
    float* hz   = ws + o; o += (size_t)N*D2;
    float* zagg = ws + o; o += (size_t)N*D2;      // becomes z
    float* zwh  = ws + o; o += (size_t)N*GD;
    float* zwt  = ws + o; o += (size_t)N*GD;
    (void)ws_size; (void)n_in; (void)out_size;

    hipMemsetAsync(dinv, 0, (size_t)N*sizeof(float), stream);
    hipMemsetAsync(agg1, 0, (size_t)N*D1*sizeof(float), stream);
    hipMemsetAsync(zagg, 0, (size_t)N*D2*sizeof(float), stream);

    k_deg <<<dim3((E+255)/256), dim3(256), 0, stream>>>(dst, dinv, E);
    k_dinv<<<dim3((N+255)/256), dim3(256), 0, stream>>>(dinv, N);
    k_h1  <<<dim3((N+3)/4),     dim3(256), 0, stream>>>(x, W1, h1, N);
    k_scat1<<<dim3((E*D1+255)/256), dim3(256), 0, stream>>>(src, dst, dinv, h1, agg1, E);
    k_relu<<<dim3((N*D1+255)/256), dim3(256), 0, stream>>>(agg1, h1, dinv, b1, N);
    k_hz  <<<dim3(N), dim3(128), 0, stream>>>(agg1, W2, hz, N);
    k_scat2<<<dim3(((size_t)E*D2+255)/256), dim3(256), 0, stream>>>(src, dst, dinv, hz, zagg, E);
    k_zfin<<<dim3((N*D2+255)/256), dim3(256), 0, stream>>>(zagg, hz, dinv, b2, N);
    k_zw  <<<dim3((N+15)/16), dim3(384), 0, stream>>>(zagg, Wih, zwh, zwt, N);
    k_big <<<dim3((T+BM-1)/BM), dim3(256), 0, stream>>>(remb, Wih, zwh, zwt, b_ih, b_hh, trip, score, T);
}

// Round 2
// 604.029 us; speedup vs baseline: 4.7040x; 4.7040x over previous
//
#include <hip/hip_runtime.h>

#define NF 768
#define D1 10
#define D2 128
#define GD 384
#define BM 128
#define BK 32

typedef __attribute__((ext_vector_type(8))) short bf16x8;
typedef __attribute__((ext_vector_type(16))) float f32x16;

static __device__ __forceinline__ float sigf(float v){ return 1.0f/(1.0f+__expf(-v)); }
static __device__ __forceinline__ float tanhfast(float v){ return 2.0f/(1.0f+__expf(-2.0f*v)) - 1.0f; }
static __device__ __forceinline__ short f2bf(float f){
    unsigned u = __float_as_uint(f);
    u += 0x7fffu + ((u>>16)&1u);
    return (short)(u>>16);
}

// ---- degree via atomics ----
__global__ void k_deg(const int* __restrict__ dst, float* __restrict__ deg, int E){
    int e = blockIdx.x*256 + threadIdx.x;
    if(e<E) atomicAdd(&deg[dst[e]], 1.0f);
}
__global__ void k_dinv(float* deg, int N){
    int n = blockIdx.x*256 + threadIdx.x;
    if(n<N) deg[n] = rsqrtf(deg[n]+1.0f);
}

// ---- h1 = x @ W1 ----
__global__ __launch_bounds__(256) void k_h1(const float* __restrict__ x,
                                            const float* __restrict__ W1,
                                            float* __restrict__ h1, int N){
    __shared__ float w1s[NF*D1];
    for(int i=threadIdx.x;i<NF*D1;i+=256) w1s[i]=W1[i];
    __syncthreads();
    int row = blockIdx.x*4 + (threadIdx.x>>6);
    int lane = threadIdx.x&63;
    if(row>=N) return;
    const float* xr = x + (size_t)row*NF;
    float acc[D1];
#pragma unroll
    for(int c=0;c<D1;c++) acc[c]=0.f;
#pragma unroll
    for(int i=0;i<NF/64;i++){
        float xa = xr[lane+64*i];
        const float* w = &w1s[(lane+64*i)*D1];
#pragma unroll
        for(int c=0;c<D1;c++) acc[c] += xa*w[c];
    }
#pragma unroll
    for(int c=0;c<D1;c++){
        float v=acc[c];
#pragma unroll
        for(int off=32;off;off>>=1) v += __shfl_down(v,off,64);
        if(lane==0) h1[(size_t)row*D1+c]=v;
    }
}

__global__ void k_scat1(const int* __restrict__ src, const int* __restrict__ dst,
                        const float* __restrict__ dinv, const float* __restrict__ h1,
                        float* __restrict__ agg1, int E){
    int gid = blockIdx.x*256 + threadIdx.x;
    if(gid >= E*D1) return;
    int e = gid/D1, c = gid - e*D1;
    int s = src[e], d = dst[e];
    float norm = dinv[s]*dinv[d];
    atomicAdd(&agg1[(size_t)d*D1+c], h1[(size_t)s*D1+c]*norm);
}

__global__ void k_relu(float* __restrict__ agg1, const float* __restrict__ h1,
                       const float* __restrict__ dinv, const float* __restrict__ b1, int N){
    int gid = blockIdx.x*256 + threadIdx.x;
    if(gid >= N*D1) return;
    int n = gid/D1, c = gid - n*D1;
    float di = dinv[n];
    float v = agg1[gid] + h1[gid]*di*di + b1[c];
    agg1[gid] = v>0.f ? v : 0.f;
}

__global__ __launch_bounds__(128) void k_hz(const float* __restrict__ h,
                                            const float* __restrict__ W2,
                                            float* __restrict__ hz, int N){
    __shared__ float w2s[D1*D2];
    int j = threadIdx.x;
    for(int i=j;i<D1*D2;i+=128) w2s[i]=W2[i];
    __syncthreads();
    int n = blockIdx.x;
    if(n>=N) return;
    const float* hr = h + (size_t)n*D1;
    float acc=0.f;
#pragma unroll
    for(int k=0;k<D1;k++) acc += hr[k]*w2s[k*D2+j];
    hz[(size_t)n*D2+j]=acc;
}

__global__ void k_scat2(const int* __restrict__ src, const int* __restrict__ dst,
                        const float* __restrict__ dinv, const float* __restrict__ hz,
                        float* __restrict__ zagg, int E){
    int gid = blockIdx.x*256 + threadIdx.x;
    int e = gid>>7, c = gid&127;
    if(e>=E) return;
    int s=src[e], d=dst[e];
    float norm = dinv[s]*dinv[d];
    atomicAdd(&zagg[(size_t)d*D2+c], hz[(size_t)s*D2+c]*norm);
}

__global__ void k_zfin(float* __restrict__ zagg, const float* __restrict__ hz,
                       const float* __restrict__ dinv, const float* __restrict__ b2, int N){
    int gid = blockIdx.x*256 + threadIdx.x;
    if(gid >= N*D2) return;
    int n = gid>>7, c = gid&127;
    float di = dinv[n];
    zagg[gid] = zagg[gid] + hz[gid]*di*di + b2[c];
}

// ---- zwh/zwt tables: zwh[n][j] = z[n].W_ih[rw(j)][0:128], zwt cols 896:1024 ----
__global__ __launch_bounds__(384) void k_zw(const float* __restrict__ z,
                                            const float* __restrict__ Wih,
                                            float* __restrict__ zwh, float* __restrict__ zwt, int N){
    __shared__ float As[16*D2];
    int n0 = blockIdx.x*16;
    int tid = threadIdx.x;
    for(int idx=tid; idx<16*D2; idx+=384){
        int m=idx>>7, k=idx&127;
        As[idx] = (n0+m<N) ? z[(size_t)(n0+m)*D2 + k] : 0.f;
    }
    __syncthreads();
    int row = tid<128 ? tid : tid+128;
    const float* wh = Wih + (size_t)row*1024;
    const float* wt = wh + 896;
    float ah[16], at[16];
#pragma unroll
    for(int m=0;m<16;m++){ ah[m]=0.f; at[m]=0.f; }
    for(int k=0;k<D2;k++){
        float bh=wh[k], bt=wt[k];
#pragma unroll
        for(int m=0;m<16;m++){ float a=As[m*D2+k]; ah[m]+=a*bh; at[m]+=a*bt; }
    }
    for(int m=0;m<16;m++){
        if(n0+m<N){
            zwh[(size_t)(n0+m)*GD + tid] = ah[m];
            zwt[(size_t)(n0+m)*GD + tid] = at[m];
        }
    }
}

// ---- W_ih rows {i:0..128, g:256..384, o:384..512}, cols 128..896 -> bf16, permuted col order ----
// staged col c = wn*96 + gate*32 + dd  <->  W row gbase[gate] + wn*32 + dd
__global__ void k_wconv(const float* __restrict__ Wih, ushort* __restrict__ Wb){
    int gid = blockIdx.x*256 + threadIdx.x;       // 384*96 = 36864 chunks of 8
    if(gid >= GD*(NF/8)) return;
    int c = gid/(NF/8);
    int s = gid - c*(NF/8);
    int kk = s*8;
    int wnc = c/96, r = c - wnc*96, gi = r>>5, dd = r&31;
    int gbase = (gi==0) ? 0 : ((gi==1) ? 256 : 384);
    int wrow = gbase + wnc*32 + dd;
    const float* p = Wih + (size_t)wrow*1024 + 128 + kk;
    float4 v0 = *(const float4*)p;
    float4 v1 = *(const float4*)(p+4);
    bf16x8 o;
    o[0]=f2bf(v0.x); o[1]=f2bf(v0.y); o[2]=f2bf(v0.z); o[3]=f2bf(v0.w);
    o[4]=f2bf(v1.x); o[5]=f2bf(v1.y); o[6]=f2bf(v1.z); o[7]=f2bf(v1.w);
    *(bf16x8*)(Wb + (size_t)c*NF + kk) = o;
}

// ---- fused MFMA GEMM (r_emb x Wb^T) + LSTM epilogue ----
__global__ __launch_bounds__(512,2) void k_big(
    const float* __restrict__ remb, const ushort* __restrict__ Wb,
    const float* __restrict__ zwh, const float* __restrict__ zwt,
    const float* __restrict__ b_ih, const float* __restrict__ b_hh,
    const int* __restrict__ trip, float* __restrict__ score, int T)
{
    __shared__ ushort As[4*2*64*8];     //  8 KB: fragidx(mb*2+kh)*64 + lane, 8 bf16 each
    __shared__ ushort Bs[12*2*64*8];    // 24 KB
    __shared__ float rowsum[BM];
    __shared__ int sh_th[BM], sh_tt[BM];

    int tid = threadIdx.x;
    int lane = tid & 63;
    int wid = tid >> 6, wm = wid >> 2, wn = wid & 3;
    int l31 = lane & 31, lh = lane >> 5;
    int t0 = blockIdx.x * BM;

    if(tid < BM){
        rowsum[tid] = 0.f;
        int t = t0 + tid; int tc = (t < T) ? t : T-1;
        sh_th[tid] = trip[3*tc];
        sh_tt[tid] = trip[3*tc+2];
    }

    // staging geometry: thread -> (row, k-chunk) permuted so ds_write slots are phase-linear
    const int arow = (tid&7) + 8*(tid>>5);           // 0..127
    const int akb  = (tid>>3)&1, akh = (tid>>4)&1;
    const int akk  = akb*8 + akh*16;
    const int aslot = ((((arow>>5)*2 + akh)*64) + (arow&31) + 32*akb)*8;
    const size_t arowg = (size_t)((t0+arow < T) ? (t0+arow) : (T-1)) * NF;

    int bcol[3], bkk[3], bslot[3];
#pragma unroll
    for(int i=0;i<3;i++){
        int seg = tid + 512*i;
        int col = (seg&7) + 8*(seg>>5);              // 0..383
        int kb = (seg>>3)&1, kh = (seg>>4)&1;
        bcol[i] = col; bkk[i] = kb*8 + kh*16;
        bslot[i] = ((((col>>5)*2 + kh)*64) + (col&31) + 32*kb)*8;
    }

    // prefetch k-step 0
    float4 pa0 = *(const float4*)(remb + arowg + akk);
    float4 pa1 = *(const float4*)(remb + arowg + akk + 4);
    int4 pb0 = *(const int4*)(Wb + (size_t)bcol[0]*NF + bkk[0]);
    int4 pb1 = *(const int4*)(Wb + (size_t)bcol[1]*NF + bkk[1]);
    int4 pb2 = *(const int4*)(Wb + (size_t)bcol[2]*NF + bkk[2]);

    f32x16 acc[2][3];
    const f32x16 zero = {0,0,0,0,0,0,0,0,0,0,0,0,0,0,0,0};
#pragma unroll
    for(int m=0;m<2;m++)
#pragma unroll
        for(int n=0;n<3;n++) acc[m][n]=zero;

    for(int ks=0; ks<NF/BK; ++ks){
        {   // stage A (cvt fp32 -> bf16)
            bf16x8 av;
            av[0]=f2bf(pa0.x); av[1]=f2bf(pa0.y); av[2]=f2bf(pa0.z); av[3]=f2bf(pa0.w);
            av[4]=f2bf(pa1.x); av[5]=f2bf(pa1.y); av[6]=f2bf(pa1.z); av[7]=f2bf(pa1.w);
            *(bf16x8*)(&As[aslot]) = av;
        }
        *(int4*)(&Bs[bslot[0]]) = pb0;
        *(int4*)(&Bs[bslot[1]]) = pb1;
        *(int4*)(&Bs[bslot[2]]) = pb2;
        if(ks+1 < NF/BK){
            int k0n = (ks+1)*BK;
            pa0 = *(const float4*)(remb + arowg + k0n + akk);
            pa1 = *(const float4*)(remb + arowg + k0n + akk + 4);
            pb0 = *(const int4*)(Wb + (size_t)bcol[0]*NF + k0n + bkk[0]);
            pb1 = *(const int4*)(Wb + (size_t)bcol[1]*NF + k0n + bkk[1]);
            pb2 = *(const int4*)(Wb + (size_t)bcol[2]*NF + k0n + bkk[2]);
        }
        __syncthreads();
#pragma unroll
        for(int kh=0; kh<2; kh++){
            bf16x8 a0 = *(const bf16x8*)&As[(((wm*2+0)*2+kh)*64 + lane)*8];
            bf16x8 a1 = *(const bf16x8*)&As[(((wm*2+1)*2+kh)*64 + lane)*8];
            bf16x8 b0 = *(const bf16x8*)&Bs[(((wn*3+0)*2+kh)*64 + lane)*8];
            bf16x8 b1 = *(const bf16x8*)&Bs[(((wn*3+1)*2+kh)*64 + lane)*8];
            bf16x8 b2 = *(const bf16x8*)&Bs[(((wn*3+2)*2+kh)*64 + lane)*8];
            acc[0][0] = __builtin_amdgcn_mfma_f32_32x32x16_bf16(a0,b0,acc[0][0],0,0,0);
            acc[0][1] = __builtin_amdgcn_mfma_f32_32x32x16_bf16(a0,b1,acc[0][1],0,0,0);
            acc[0][2] = __builtin_amdgcn_mfma_f32_32x32x16_bf16(a0,b2,acc[0][2],0,0,0);
            acc[1][0] = __builtin_amdgcn_mfma_f32_32x32x16_bf16(a1,b0,acc[1][0],0,0,0);
            acc[1][1] = __builtin_amdgcn_mfma_f32_32x32x16_bf16(a1,b1,acc[1][1],0,0,0);
            acc[1][2] = __builtin_amdgcn_mfma_f32_32x32x16_bf16(a1,b2,acc[1][2],0,0,0);
        }
        __syncthreads();
    }

    // epilogue: acc[m][gate], col d = wn*32 + l31, row = wm*64 + m*32 + (r&3)+8*(r>>2)+4*lh
    int d = wn*32 + l31;
    float bi = b_ih[d]     + b_hh[d];
    float bg = b_ih[256+d] + b_hh[256+d];
    float bo = b_ih[384+d] + b_hh[384+d];
#pragma unroll
    for(int m=0;m<2;m++){
#pragma unroll
        for(int r=0;r<16;r++){
            int row = wm*64 + m*32 + (r&3) + 8*(r>>2) + 4*lh;
            int t = t0 + row;
            float ov = 0.f;
            if(t < T){
                const float* zh = zwh + (size_t)sh_th[row]*GD;
                const float* zt = zwt + (size_t)sh_tt[row]*GD;
                float ig = acc[m][0][r] + zh[d]     + zt[d]     + bi;
                float gg = acc[m][1][r] + zh[128+d] + zt[128+d] + bg;
                float og = acc[m][2][r] + zh[256+d] + zt[256+d] + bo;
                float cc = sigf(ig)*tanhfast(gg);
                ov = sigf(og)*tanhfast(cc);
            }
#pragma unroll
            for(int off=1; off<32; off<<=1) ov += __shfl_xor(ov, off, 64);
            if(l31==0) atomicAdd(&rowsum[row], ov);
        }
    }
    __syncthreads();
    if(tid < BM){
        int t = t0 + tid;
        if(t < T) score[t] = sigf(rowsum[tid]);
    }
}

extern "C" void kernel_launch(void* const* d_in, const int* in_sizes, int n_in,
                              void* d_out, int out_size, void* d_ws, size_t ws_size,
                              hipStream_t stream){
    const float* x    = (const float*)d_in[0];
    const float* remb = (const float*)d_in[1];
    const float* W1   = (const float*)d_in[2];
    const float* b1   = (const float*)d_in[3];
    const float* W2   = (const float*)d_in[4];
    const float* b2   = (const float*)d_in[5];
    const float* Wih  = (const float*)d_in[6];
    const float* b_ih = (const float*)d_in[8];
    const float* b_hh = (const float*)d_in[9];
    const int*   ei   = (const int*)d_in[10];
    const int*   trip = (const int*)d_in[11];
    float* score = (float*)d_out;

    const int N = in_sizes[0]/NF;
    const int E = in_sizes[10]/2;
    const int T = in_sizes[11]/3;
    const int* src = ei;
    const int* dst = ei + E;

    float* ws = (float*)d_ws;
    size_t o = 0;
    ushort* Wb = (ushort*)ws;        o += (size_t)GD*NF/2;   // bf16 W, 589824 B
    float* dinv = ws + o; o += (size_t)((N+7)&~7);
    float* h1   = ws + o; o += (size_t)N*D1;
    float* agg1 = ws + o; o += (size_t)N*D1;
    float* hz   = ws + o; o += (size_t)N*D2;
    float* zagg = ws + o; o += (size_t)N*D2;
    float* zwh  = ws + o; o += (size_t)N*GD;
    float* zwt  = ws + o; o += (size_t)N*GD;
    (void)ws_size; (void)n_in; (void)out_size;

    hipMemsetAsync(dinv, 0, (size_t)N*sizeof(float), stream);
    hipMemsetAsync(agg1, 0, (size_t)N*D1*sizeof(float), stream);
    hipMemsetAsync(zagg, 0, (size_t)N*D2*sizeof(float), stream);

    k_wconv<<<dim3((GD*(NF/8)+255)/256), dim3(256), 0, stream>>>(Wih, Wb);
    k_deg <<<dim3((E+255)/256), dim3(256), 0, stream>>>(dst, dinv, E);
    k_dinv<<<dim3((N+255)/256), dim3(256), 0, stream>>>(dinv, N);
    k_h1  <<<dim3((N+3)/4),     dim3(256), 0, stream>>>(x, W1, h1, N);
    k_scat1<<<dim3((E*D1+255)/256), dim3(256), 0, stream>>>(src, dst, dinv, h1, agg1, E);
    k_relu<<<dim3((N*D1+255)/256), dim3(256), 0, stream>>>(agg1, h1, dinv, b1, N);
    k_hz  <<<dim3(N), dim3(128), 0, stream>>>(agg1, W2, hz, N);
    k_scat2<<<dim3(((size_t)E*D2+255)/256), dim3(256), 0, stream>>>(src, dst, dinv, hz, zagg, E);
    k_zfin<<<dim3((N*D2+255)/256), dim3(256), 0, stream>>>(zagg, hz, dinv, b2, N);
    k_zw  <<<dim3((N+15)/16), dim3(384), 0, stream>>>(zagg, Wih, zwh, zwt, N);
    k_big <<<dim3((T+BM-1)/BM), dim3(512), 0, stream>>>(remb, Wb, zwh, zwt, b_ih, b_hh, trip, score, T);
}

// Round 3
// 363.031 us; speedup vs baseline: 7.8267x; 1.6638x over previous
//
#include <hip/hip_runtime.h>

#define NF 768
#define D1 10
#define D2 128
#define BM 64
#define NS 24        // NF/32

typedef __attribute__((ext_vector_type(8))) short bf16x8;
typedef __attribute__((ext_vector_type(16))) float f32x16;

static __device__ __forceinline__ float sigf(float v){ return 1.0f/(1.0f+__expf(-v)); }
static __device__ __forceinline__ float tanhfast(float v){ return 2.0f/(1.0f+__expf(-2.0f*v)) - 1.0f; }
static __device__ __forceinline__ short f2bf(float f){
    unsigned u = __float_as_uint(f);
    u += 0x7fffu + ((u>>16)&1u);
    return (short)(u>>16);
}
static __device__ __forceinline__ float bf2f(ushort h){
    return __uint_as_float(((unsigned)h)<<16);
}

// ---- degree counts (int) ----
__global__ void k_deg(const int* __restrict__ dst, int* __restrict__ cnt, int E){
    int e = blockIdx.x*256 + threadIdx.x;
    if(e<E) atomicAdd(&cnt[dst[e]], 1);
}
__global__ void k_dinv(const int* __restrict__ cnt, float* __restrict__ dinv, int N){
    int n = blockIdx.x*256 + threadIdx.x;
    if(n<N) dinv[n] = rsqrtf((float)cnt[n] + 1.0f);
}

// ---- exclusive prefix scan of cnt -> rowptr, rowcur (single block) ----
__global__ __launch_bounds__(256) void k_scan(const int* __restrict__ cnt,
                                              int* __restrict__ rowptr,
                                              int* __restrict__ rowcur, int N, int E){
    __shared__ int part[256];
    int t = threadIdx.x;
    int C = (N+255)/256;
    int lo = t*C, hi = lo+C; if(hi>N) hi=N; if(lo>N) lo=N;
    int s=0;
    for(int i=lo;i<hi;i++) s += cnt[i];
    part[t]=s;
    __syncthreads();
    if(t==0){
        int run=0;
        for(int i=0;i<256;i++){ int v=part[i]; part[i]=run; run+=v; }
        rowptr[N]=E;
    }
    __syncthreads();
    int run = part[t];
    for(int i=lo;i<hi;i++){ rowptr[i]=run; rowcur[i]=run; run += cnt[i]; }
}

// ---- fill CSR: esrc (source node), enorm (edge weight) sorted by dst ----
__global__ void k_fill(const int* __restrict__ src, const int* __restrict__ dst,
                       const float* __restrict__ dinv, int* __restrict__ rowcur,
                       int* __restrict__ esrc, float* __restrict__ enorm, int E){
    int e = blockIdx.x*256 + threadIdx.x;
    if(e>=E) return;
    int s=src[e], d=dst[e];
    int pos = atomicAdd(&rowcur[d], 1);
    esrc[pos]=s;
    enorm[pos]=dinv[s]*dinv[d];
}

// ---- h1 = x @ W1 ----
__global__ __launch_bounds__(256) void k_h1(const float* __restrict__ x,
                                            const float* __restrict__ W1,
                                            float* __restrict__ h1, int N){
    __shared__ float w1s[NF*D1];
    for(int i=threadIdx.x;i<NF*D1;i+=256) w1s[i]=W1[i];
    __syncthreads();
    int row = blockIdx.x*4 + (threadIdx.x>>6);
    int lane = threadIdx.x&63;
    if(row>=N) return;
    const float* xr = x + (size_t)row*NF;
    float acc[D1];
#pragma unroll
    for(int c=0;c<D1;c++) acc[c]=0.f;
#pragma unroll
    for(int i=0;i<NF/64;i++){
        float xa = xr[lane+64*i];
        const float* w = &w1s[(lane+64*i)*D1];
#pragma unroll
        for(int c=0;c<D1;c++) acc[c] += xa*w[c];
    }
#pragma unroll
    for(int c=0;c<D1;c++){
        float v=acc[c];
#pragma unroll
        for(int off=32;off;off>>=1) v += __shfl_down(v,off,64);
        if(lane==0) h1[(size_t)row*D1+c]=v;
    }
}

__global__ void k_scat1(const int* __restrict__ src, const int* __restrict__ dst,
                        const float* __restrict__ dinv, const float* __restrict__ h1,
                        float* __restrict__ agg1, int E){
    int gid = blockIdx.x*256 + threadIdx.x;
    if(gid >= E*D1) return;
    int e = gid/D1, c = gid - e*D1;
    int s = src[e], d = dst[e];
    float norm = dinv[s]*dinv[d];
    atomicAdd(&agg1[(size_t)d*D1+c], h1[(size_t)s*D1+c]*norm);
}

__global__ void k_relu(float* __restrict__ agg1, const float* __restrict__ h1,
                       const float* __restrict__ dinv, const float* __restrict__ b1, int N){
    int gid = blockIdx.x*256 + threadIdx.x;
    if(gid >= N*D1) return;
    int n = gid/D1, c = gid - n*D1;
    float di = dinv[n];
    float v = agg1[gid] + h1[gid]*di*di + b1[c];
    agg1[gid] = v>0.f ? v : 0.f;
}

__global__ __launch_bounds__(128) void k_hz(const float* __restrict__ h,
                                            const float* __restrict__ W2,
                                            float* __restrict__ hz, int N){
    __shared__ float w2s[D1*D2];
    int j = threadIdx.x;
    for(int i=j;i<D1*D2;i+=128) w2s[i]=W2[i];
    __syncthreads();
    int n = blockIdx.x;
    if(n>=N) return;
    const float* hr = h + (size_t)n*D1;
    float acc=0.f;
#pragma unroll
    for(int k=0;k<D1;k++) acc += hr[k]*w2s[k*D2+j];
    hz[(size_t)n*D2+j]=acc;
}

// ---- layer-2 aggregation via CSR gather (fuses zfin): z = gather + self + b2 ----
__global__ __launch_bounds__(128) void k_gath2(const float* __restrict__ hz,
        const int* __restrict__ rowptr, const int* __restrict__ esrc,
        const float* __restrict__ enorm, const float* __restrict__ dinv,
        const float* __restrict__ b2, float* __restrict__ z, int N){
    int n = blockIdx.x;
    int c = threadIdx.x;
    int e0 = rowptr[n], e1 = rowptr[n+1];
    float di = dinv[n];
    float acc = hz[(size_t)n*D2+c]*di*di + b2[c];
    int e = e0;
    for(; e+1<e1; e+=2){
        int s0=esrc[e], s1=esrc[e+1];
        float w0=enorm[e], w1=enorm[e+1];
        acc += hz[(size_t)s0*D2+c]*w0 + hz[(size_t)s1*D2+c]*w1;
    }
    if(e<e1) acc += hz[(size_t)esrc[e]*D2+c]*enorm[e];
    z[(size_t)n*D2+c]=acc;
}

// ---- big-GEMM B fragment image: 12 frags x 48 ks16 x 64 lanes x 8 bf16 ----
// staged col = wn*96 + gi*32 + dd  <->  W row gbase(gi)+wn*32+dd; W col 128+k
__global__ void k_wimgB(const float* __restrict__ Wih, ushort* __restrict__ img){
    int gid = blockIdx.x*256 + threadIdx.x;        // 12*48*64 = 36864
    if(gid >= 12*48*64) return;
    int l = gid & 63;
    int ks16 = (gid>>6) % 48;
    int f = gid / (48*64);
    int dd = l & 31, kb = l>>5;
    int wn = f/3, gi = f - wn*3;
    int gbase = (gi==0)?0:((gi==1)?256:384);
    int wrow = gbase + wn*32 + dd;
    int k = ks16*16 + kb*8;
    const float* p = Wih + (size_t)wrow*1024 + 128 + k;
    float4 v0=*(const float4*)p, v1=*(const float4*)(p+4);
    bf16x8 o;
    o[0]=f2bf(v0.x); o[1]=f2bf(v0.y); o[2]=f2bf(v0.z); o[3]=f2bf(v0.w);
    o[4]=f2bf(v1.x); o[5]=f2bf(v1.y); o[6]=f2bf(v1.z); o[7]=f2bf(v1.w);
    *(bf16x8*)(img + (size_t)gid*8) = o;
}

// ---- zw B image: 24 frags x 8 ks16 x 64 lanes x 8 bf16 (combined zwh|zwt cols) ----
__global__ void k_wimgZ(const float* __restrict__ Wih, ushort* __restrict__ img){
    int gid = blockIdx.x*256 + threadIdx.x;        // 24*8*64 = 12288
    if(gid >= 24*8*64) return;
    int l = gid & 63;
    int ks16 = (gid>>6) & 7;
    int f = gid >> 9;
    int j = f*32 + (l&31);
    int kb = l>>5;
    int k = ks16*16 + kb*8;
    int jq = (j<384)? j : j-384;
    int wrow = (jq<128)? jq : jq+128;
    int wcol = (j<384)? k : (896+k);
    const float* p = Wih + (size_t)wrow*1024 + wcol;
    float4 v0=*(const float4*)p, v1=*(const float4*)(p+4);
    bf16x8 o;
    o[0]=f2bf(v0.x); o[1]=f2bf(v0.y); o[2]=f2bf(v0.z); o[3]=f2bf(v0.w);
    o[4]=f2bf(v1.x); o[5]=f2bf(v1.y); o[6]=f2bf(v1.z); o[7]=f2bf(v1.w);
    *(bf16x8*)(img + (size_t)gid*8) = o;
}

// ---- zwht = z @ [Wh|Wt] via MFMA, bf16 out. 32 nodes/block, 4 waves x 192 cols ----
__global__ __launch_bounds__(256) void k_zw_m(const float* __restrict__ z,
                                              const ushort* __restrict__ img,
                                              ushort* __restrict__ zwht, int N){
    __shared__ ushort As[8*64*8];     // 8 KB
    int tid=threadIdx.x, lane=tid&63, w=tid>>6;
    int n0 = blockIdx.x*32;
#pragma unroll
    for(int i=0;i<2;i++){
        int s = tid + 256*i;
        int ks16 = s>>6, l = s&63;
        int row = l&31, kb=l>>5;
        int n = n0+row; if(n>=N) n=N-1;
        const float* p = z + (size_t)n*D2 + ks16*16 + kb*8;
        float4 v0=*(const float4*)p, v1=*(const float4*)(p+4);
        bf16x8 o;
        o[0]=f2bf(v0.x); o[1]=f2bf(v0.y); o[2]=f2bf(v0.z); o[3]=f2bf(v0.w);
        o[4]=f2bf(v1.x); o[5]=f2bf(v1.y); o[6]=f2bf(v1.z); o[7]=f2bf(v1.w);
        *(bf16x8*)(&As[(size_t)s*8]) = o;
    }
    __syncthreads();
    f32x16 acc[6];
    const f32x16 zer = {0,0,0,0,0,0,0,0,0,0,0,0,0,0,0,0};
#pragma unroll
    for(int nf=0;nf<6;nf++) acc[nf]=zer;
#pragma unroll
    for(int ks16=0;ks16<8;ks16++){
        bf16x8 a = *(const bf16x8*)&As[(ks16*64+lane)*8];
#pragma unroll
        for(int nf=0;nf<6;nf++){
            int f = w*6+nf;
            bf16x8 b = *(const bf16x8*)(img + ((size_t)(f*8+ks16)*64 + lane)*8);
            acc[nf] = __builtin_amdgcn_mfma_f32_32x32x16_bf16(a,b,acc[nf],0,0,0);
        }
    }
    int l31=lane&31, lh=lane>>5;
#pragma unroll
    for(int nf=0;nf<6;nf++){
        int j = (w*6+nf)*32 + l31;
#pragma unroll
        for(int r=0;r<16;r++){
            int row = (r&3)+8*(r>>2)+4*lh;
            int n = n0+row;
            if(n<N) zwht[(size_t)n*768 + j] = (ushort)f2bf(acc[nf][r]);
        }
    }
}

// ---- fused MFMA GEMM + LSTM epilogue. BM=64 rows, 4 waves (wn 0..3), B from L2 ----
__global__ __launch_bounds__(256,3) void k_big(
    const float* __restrict__ remb, const ushort* __restrict__ img,
    const ushort* __restrict__ zwht, const float* __restrict__ b_ih,
    const float* __restrict__ b_hh, const int* __restrict__ trip,
    float* __restrict__ score, int T)
{
    __shared__ ushort As[2][4*64*8];   // 2 x 4 KB double buffer
    __shared__ float rowsum[BM];
    __shared__ int sh_th[BM], sh_tt[BM];
    int tid=threadIdx.x, lane=tid&63, wn=tid>>6;
    int l31=lane&31, lh=lane>>5;
    int t0 = blockIdx.x*BM;
    if(tid<BM){
        rowsum[tid]=0.f;
        int t=t0+tid, tc=(t<T)?t:T-1;
        sh_th[tid]=trip[3*tc]; sh_tt[tid]=trip[3*tc+2];
    }
    const int arow=(tid&7)+8*(tid>>5);
    const int akb=(tid>>3)&1, akh=(tid>>4)&1;
    const int aslot = (((arow>>5)*2+akh)*64 + (arow&31)+32*akb)*8;
    const size_t arowg = (size_t)((t0+arow<T)?(t0+arow):(T-1))*NF + akb*8 + akh*16;
    const ushort* wbase = img + ((size_t)(wn*3)*48*64 + lane)*8;

    float4 p0a,p0b,p1a,p1b;
    p0a=*(const float4*)(remb+arowg);      p0b=*(const float4*)(remb+arowg+4);
    p1a=*(const float4*)(remb+arowg+32);   p1b=*(const float4*)(remb+arowg+36);

    f32x16 acc[2][3];
    const f32x16 zer = {0,0,0,0,0,0,0,0,0,0,0,0,0,0,0,0};
#pragma unroll
    for(int m=0;m<2;m++)
#pragma unroll
        for(int g=0;g<3;g++) acc[m][g]=zer;

#define STAGE(B,VA,VB) { bf16x8 o_; \
    o_[0]=f2bf(VA.x); o_[1]=f2bf(VA.y); o_[2]=f2bf(VA.z); o_[3]=f2bf(VA.w); \
    o_[4]=f2bf(VB.x); o_[5]=f2bf(VB.y); o_[6]=f2bf(VB.z); o_[7]=f2bf(VB.w); \
    *(bf16x8*)(&As[B][aslot]) = o_; }

#define COMPUTE(B,KS) { \
    _Pragma("unroll") \
    for(int kh=0;kh<2;kh++){ \
        bf16x8 a0 = *(const bf16x8*)&As[B][((0*2+kh)*64+lane)*8]; \
        bf16x8 a1 = *(const bf16x8*)&As[B][((1*2+kh)*64+lane)*8]; \
        int ksh = (KS)*2+kh; \
        bf16x8 b0 = *(const bf16x8*)(wbase + (size_t)(0*48+ksh)*512); \
        bf16x8 b1 = *(const bf16x8*)(wbase + (size_t)(1*48+ksh)*512); \
        bf16x8 b2v= *(const bf16x8*)(wbase + (size_t)(2*48+ksh)*512); \
        acc[0][0]=__builtin_amdgcn_mfma_f32_32x32x16_bf16(a0,b0 ,acc[0][0],0,0,0); \
        acc[0][1]=__builtin_amdgcn_mfma_f32_32x32x16_bf16(a0,b1 ,acc[0][1],0,0,0); \
        acc[0][2]=__builtin_amdgcn_mfma_f32_32x32x16_bf16(a0,b2v,acc[0][2],0,0,0); \
        acc[1][0]=__builtin_amdgcn_mfma_f32_32x32x16_bf16(a1,b0 ,acc[1][0],0,0,0); \
        acc[1][1]=__builtin_amdgcn_mfma_f32_32x32x16_bf16(a1,b1 ,acc[1][1],0,0,0); \
        acc[1][2]=__builtin_amdgcn_mfma_f32_32x32x16_bf16(a1,b2v,acc[1][2],0,0,0); \
    } }

    STAGE(0, p0a, p0b);
    __syncthreads();

    for(int ks=0; ks<NS; ks+=2){
        if(ks+2<NS){
            p0a=*(const float4*)(remb+arowg+(size_t)(ks+2)*32);
            p0b=*(const float4*)(remb+arowg+(size_t)(ks+2)*32+4);
        }
        STAGE(1, p1a, p1b);
        COMPUTE(0, ks);
        __syncthreads();
        if(ks+3<NS){
            p1a=*(const float4*)(remb+arowg+(size_t)(ks+3)*32);
            p1b=*(const float4*)(remb+arowg+(size_t)(ks+3)*32+4);
        }
        if(ks+2<NS){ STAGE(0, p0a, p0b); }
        COMPUTE(1, ks+1);
        __syncthreads();
    }

    // epilogue
    int d = wn*32+l31;
    float bi=b_ih[d]+b_hh[d];
    float bg=b_ih[256+d]+b_hh[256+d];
    float bo=b_ih[384+d]+b_hh[384+d];
#pragma unroll
    for(int m=0;m<2;m++){
#pragma unroll
        for(int r=0;r<16;r++){
            int row = m*32 + (r&3)+8*(r>>2)+4*lh;
            int t = t0+row;
            float ov = 0.f;
            if(t<T){
                const ushort* zh = zwht + (size_t)sh_th[row]*768;
                const ushort* zt = zwht + (size_t)sh_tt[row]*768 + 384;
                float ig = acc[m][0][r] + bf2f(zh[d])     + bf2f(zt[d])     + bi;
                float gg = acc[m][1][r] + bf2f(zh[128+d]) + bf2f(zt[128+d]) + bg;
                float og = acc[m][2][r] + bf2f(zh[256+d]) + bf2f(zt[256+d]) + bo;
                float cc = sigf(ig)*tanhfast(gg);
                ov = sigf(og)*tanhfast(cc);
            }
#pragma unroll
            for(int off=1; off<32; off<<=1) ov += __shfl_xor(ov, off, 64);
            if(l31==0) atomicAdd(&rowsum[row], ov);
        }
    }
    __syncthreads();
    if(tid < BM){
        int t = t0 + tid;
        if(t < T) score[t] = sigf(rowsum[tid]);
    }
#undef STAGE
#undef COMPUTE
}

extern "C" void kernel_launch(void* const* d_in, const int* in_sizes, int n_in,
                              void* d_out, int out_size, void* d_ws, size_t ws_size,
                              hipStream_t stream){
    const float* x    = (const float*)d_in[0];
    const float* remb = (const float*)d_in[1];
    const float* W1   = (const float*)d_in[2];
    const float* b1   = (const float*)d_in[3];
    const float* W2   = (const float*)d_in[4];
    const float* b2   = (const float*)d_in[5];
    const float* Wih  = (const float*)d_in[6];
    const float* b_ih = (const float*)d_in[8];
    const float* b_hh = (const float*)d_in[9];
    const int*   ei   = (const int*)d_in[10];
    const int*   trip = (const int*)d_in[11];
    float* score = (float*)d_out;

    const int N = in_sizes[0]/NF;       // 15000
    const int E = in_sizes[10]/2;       // 200000
    const int T = in_sizes[11]/3;       // 100000
    const int* src = ei;
    const int* dst = ei + E;

    float* ws = (float*)d_ws;
    size_t o = 0;
    ushort* WimgB = (ushort*)(ws+o); o += 12*48*64*8/2;       // 147456 floats
    ushort* WimgZ = (ushort*)(ws+o); o += 24*8*64*8/2;        // 49152 floats
    ushort* zwht  = (ushort*)(ws+o); o += (size_t)N*768/2;    // bf16 table
    int*   cnt    = (int*)(ws+o);    o += (size_t)((N+8)&~7);
    int*   rowptr = (int*)(ws+o);    o += (size_t)((N+8)&~7);
    int*   rowcur = (int*)(ws+o);    o += (size_t)((N+8)&~7);
    int*   esrc   = (int*)(ws+o);    o += (size_t)E;
    float* enorm  = ws+o;            o += (size_t)E;
    float* dinv   = ws+o;            o += (size_t)((N+7)&~7);
    float* h1     = ws+o;            o += (size_t)N*D1;
    float* agg1   = ws+o;            o += (size_t)N*D1;
    float* hz     = ws+o;            o += (size_t)N*D2;
    float* z      = ws+o;            o += (size_t)N*D2;
    (void)ws_size; (void)n_in; (void)out_size;

    hipMemsetAsync(cnt, 0, (size_t)N*sizeof(int), stream);
    hipMemsetAsync(agg1, 0, (size_t)N*D1*sizeof(float), stream);

    k_wimgB<<<dim3((12*48*64+255)/256), dim3(256), 0, stream>>>(Wih, WimgB);
    k_wimgZ<<<dim3((24*8*64+255)/256),  dim3(256), 0, stream>>>(Wih, WimgZ);
    k_deg  <<<dim3((E+255)/256), dim3(256), 0, stream>>>(dst, cnt, E);
    k_dinv <<<dim3((N+255)/256), dim3(256), 0, stream>>>(cnt, dinv, N);
    k_scan <<<dim3(1), dim3(256), 0, stream>>>(cnt, rowptr, rowcur, N, E);
    k_fill <<<dim3((E+255)/256), dim3(256), 0, stream>>>(src, dst, dinv, rowcur, esrc, enorm, E);
    k_h1   <<<dim3((N+3)/4), dim3(256), 0, stream>>>(x, W1, h1, N);
    k_scat1<<<dim3((E*D1+255)/256), dim3(256), 0, stream>>>(src, dst, dinv, h1, agg1, E);
    k_relu <<<dim3((N*D1+255)/256), dim3(256), 0, stream>>>(agg1, h1, dinv, b1, N);
    k_hz   <<<dim3(N), dim3(128), 0, stream>>>(agg1, W2, hz, N);
    k_gath2<<<dim3(N), dim3(128), 0, stream>>>(hz, rowptr, esrc, enorm, dinv, b2, z, N);
    k_zw_m <<<dim3((N+31)/32), dim3(256), 0, stream>>>(z, WimgZ, zwht, N);
    k_big  <<<dim3((T+BM-1)/BM), dim3(256), 0, stream>>>(remb, WimgB, zwht, b_ih, b_hh, trip, score, T);
}